// Round 7
// baseline (277.209 us; speedup 1.0000x reference)
//
#include <hip/hip_runtime.h>
#include <hip/hip_fp16.h>

// Problem constants (fixed-size problem)
#define NNODES 100000
#define NEDGES 1600000
#define IN_C   128
#define HID_C  128
#define OUT_C  64

// Padded adjacency: deg ~ Poisson(16); P(deg>=64) ~ 3e-22/node. Overflow
// list keeps exactness for any input.
#define CAP     64
#define OVF_MAX 4096

// R14: fusion round. gather1 is at its structural floor (FETCH = 8 XCD x
// 25.6 MB table, fabric-fill-bound at ~3.1 TB/s; TPN halving was flat), so
// attack serialized non-gather time instead:
//  - GEMMs are now UNSCALED (gathers apply dinv per-edge) -> GEMM1 no longer
//    depends on the adjacency build.
//  - fusedA = {binA | GEMM1} by block-range split (GEMM fills binA's
//    atomic-latency bubbles).
//  - fusedG = {gather1 + relu + GEMM2 in-block} -> hidden never hits HBM
//    (25.6 MB write + 25.6 MB read removed) and one launch disappears.
//  - binB absorbs fixup (replays ovfA for its bucket); zero absorbs detect.
//  5 launches total (was 9).
#define BUCKET_SHIFT 7
#define BUCKET_NODES 128
#define NB ((NNODES + BUCKET_NODES - 1) / BUCKET_NODES)  // 782
#define BCAP 3072     // expected 2046/bucket (Poisson, ~23 sigma guard)
#define BCNT_STRIDE 16  // one counter per 64B line
#define EB 4096       // edges per binA block
#define NBLK_A ((NEDGES + EB - 1) / EB)  // 391
#define GB ((NNODES + 63) / 64)          // 1563 64-row tiles

typedef __attribute__((ext_vector_type(8))) _Float16 half8;
typedef __attribute__((ext_vector_type(4))) _Float16 half4;
typedef __attribute__((ext_vector_type(4))) float floatx4;

// ---------------------------------------------------------------------------
// Index width handling (int64 per reference vs int32 from JAX default)
// ---------------------------------------------------------------------------
__device__ __forceinline__ long long load_idx(const void* p, long long i, int is64) {
  return is64 ? ((const long long*)p)[i] : (long long)((const int*)p)[i];
}

// zero bcnt/counters + detect index width (block 0, wave 0)
__global__ void zero_detect_kernel(const void* eidx, int* flag, int* bcnt,
                                   int* ovf_cnt, int* ovfA_cnt) {
  int i = blockIdx.x * 256 + threadIdx.x;
  if (i < NB * BCNT_STRIDE) bcnt[i] = 0;
  if (i == 0) { *ovf_cnt = 0; *ovfA_cnt = 0; }
  if (blockIdx.x == 0 && threadIdx.x < 64) {  // wave-uniform branch
    const unsigned* w = (const unsigned*)eidx;
    unsigned v = w[2 * threadIdx.x + 1];
    unsigned long long bad = __ballot(v != 0u);
    if (threadIdx.x == 0) *flag = (bad == 0ull) ? 1 : 0;
  }
}

// ===========================================================================
// fusedA: blocks [0,NBLK_A) = binA (histogram+reserve+place);
//         blocks [NBLK_A, NBLK_A+GB) = GEMM1 tile (h1 = fp16(x @ W1), unscaled)
// ===========================================================================
__global__ __launch_bounds__(256) void binA_gemm1_kernel(
    const void* __restrict__ eidx, const int* __restrict__ flag,
    int* __restrict__ bcnt, unsigned* __restrict__ buf,
    int* __restrict__ ovfA_cnt, int2* __restrict__ ovfA,
    const float* __restrict__ x, const float* __restrict__ W1,
    _Float16* __restrict__ h1) {
  __shared__ alignas(16) char smem[52224];
  const int tid = threadIdx.x;

  if (blockIdx.x < NBLK_A) {
    // ---------------- binA ----------------
    unsigned* se = (unsigned*)smem;                       // 16384 B
    unsigned short* be = (unsigned short*)(smem + 16384); //  8192 B
    int* hist = (int*)(smem + 24576);                     //  3128 B
    int* base = (int*)(smem + 27712);                     //  3128 B
    int* ofs  = (int*)(smem + 30848);                     //  3128 B (tot 33976)

    const int e0 = blockIdx.x * EB;
    const int e1 = min(e0 + EB, NEDGES);
    const int m = e1 - e0;
    const int is64 = *flag;

    for (int b = tid; b < NB; b += 256) { hist[b] = 0; ofs[b] = 0; }
    __syncthreads();

    // phase 1: single decode pass + stash + histogram
    for (int k = tid; k < m; k += 256) {
      int e = e0 + k;
      int s = (int)load_idx(eidx, e, is64);
      int d = (int)load_idx(eidx, (long long)NEDGES + e, is64);
      int b = d >> BUCKET_SHIFT;
      se[k] = (unsigned)s | ((unsigned)(d & (BUCKET_NODES - 1)) << 17);
      be[k] = (unsigned short)b;
      atomicAdd(&hist[b], 1);
    }
    __syncthreads();

    // phase 2: bulk-reserve (rotated start; padded counters = no line sharing)
    int rot = (blockIdx.x * 131) % NB;
    for (int idx = tid; idx < NB; idx += 256) {
      int b = idx + rot;
      if (b >= NB) b -= NB;
      int h = hist[b];
      if (h > 0) base[b] = atomicAdd(&bcnt[b * BCNT_STRIDE], h);
    }
    __syncthreads();

    // phase 3: place from LDS stash
    for (int k = tid; k < m; k += 256) {
      unsigned u = se[k];
      int b = be[k];
      int ko = atomicAdd(&ofs[b], 1);
      int slot = base[b] + ko;
      if (slot < BCAP) {
        buf[(size_t)b * BCAP + slot] = u;
      } else {
        int p = atomicAdd(ovfA_cnt, 1);
        if (p < OVF_MAX)
          ovfA[p] = make_int2((int)(u & 0x1FFFFu),
                              (b << BUCKET_SHIFT) | (int)(u >> 17));
      }
    }
  } else {
    // ---------------- GEMM1: h1 = fp16(x @ W1), 64-row tile ----------------
    constexpr int K = IN_C, N = HID_C, KP = K + 8;
    _Float16* Alds = (_Float16*)smem;             // 64*136*2 = 17408 B
    _Float16* Wlds = (_Float16*)(smem + 17408);   // 128*136*2 = 34816 B
    const int row0 = (blockIdx.x - NBLK_A) * 64;

    // stage W1 (KxN fp32 row-major) -> Wlds[n][k] fp16, 4x4 transpose
    constexpr int TILES = (K / 4) * (N / 4);
    for (int tile = tid; tile < TILES; tile += 256) {
      int kt = tile / (N / 4);
      int nt = tile % (N / 4);
      const float* wp = &W1[(4 * kt) * N + 4 * nt];
      float4 r0 = *(const float4*)(wp);
      float4 r1 = *(const float4*)(wp + N);
      float4 r2 = *(const float4*)(wp + 2 * N);
      float4 r3 = *(const float4*)(wp + 3 * N);
      half4 c0 = {(_Float16)r0.x, (_Float16)r1.x, (_Float16)r2.x, (_Float16)r3.x};
      half4 c1 = {(_Float16)r0.y, (_Float16)r1.y, (_Float16)r2.y, (_Float16)r3.y};
      half4 c2 = {(_Float16)r0.z, (_Float16)r1.z, (_Float16)r2.z, (_Float16)r3.z};
      half4 c3 = {(_Float16)r0.w, (_Float16)r1.w, (_Float16)r2.w, (_Float16)r3.w};
      *(half4*)&Wlds[(4 * nt + 0) * KP + 4 * kt] = c0;
      *(half4*)&Wlds[(4 * nt + 1) * KP + 4 * kt] = c1;
      *(half4*)&Wlds[(4 * nt + 2) * KP + 4 * kt] = c2;
      *(half4*)&Wlds[(4 * nt + 3) * KP + 4 * kt] = c3;
    }
    // stage A tile (64 x K fp32) -> Alds fp16
    constexpr int F4PR = K / 4;
    for (int idx = tid; idx < 64 * F4PR; idx += 256) {
      int lr = idx / F4PR;
      int c4 = (idx % F4PR) * 4;
      int gr = row0 + lr;
      if (gr > NNODES - 1) gr = NNODES - 1;
      float4 v = *(const float4*)&x[(size_t)gr * K + c4];
      half4 h = {(_Float16)v.x, (_Float16)v.y, (_Float16)v.z, (_Float16)v.w};
      *(half4*)&Alds[lr * KP + c4] = h;
    }
    __syncthreads();

    const int w = tid >> 6;
    const int lane = tid & 63;
    const int g = lane >> 4;
    const int mi = lane & 15;
    constexpr int NT = N / 16;
    floatx4 acc[NT];
#pragma unroll
    for (int t = 0; t < NT; ++t) acc[t] = (floatx4){0.f, 0.f, 0.f, 0.f};
    const _Float16* arow = &Alds[(w * 16 + mi) * KP];
#pragma unroll
    for (int ks = 0; ks < K / 32; ++ks) {
      half8 a = *(const half8*)(arow + ks * 32 + g * 8);
#pragma unroll
      for (int t = 0; t < NT; ++t) {
        half8 b = *(const half8*)&Wlds[(t * 16 + mi) * KP + ks * 32 + g * 8];
        acc[t] = __builtin_amdgcn_mfma_f32_16x16x32_f16(a, b, acc[t], 0, 0, 0);
      }
    }
#pragma unroll
    for (int r = 0; r < 4; ++r) {
      int grow = row0 + w * 16 + 4 * g + r;
      if (grow < NNODES) {
        _Float16* orow = h1 + (size_t)grow * N + mi;
#pragma unroll
        for (int t = 0; t < NT; ++t) orow[t * 16] = (_Float16)acc[t][r];
      }
    }
  }
}

// ===========================================================================
// Pass B: one block per bucket; replays its contiguous edge list + the (tiny)
// ovfA spill for its bucket through LDS atomics; writes pad tile, cnt, dinv.
// ===========================================================================
__global__ __launch_bounds__(256) void binB_kernel(const int* __restrict__ bcnt,
                                                   const unsigned* __restrict__ buf,
                                                   const int* __restrict__ ovfA_cnt,
                                                   const int2* __restrict__ ovfA,
                                                   int* __restrict__ cnt,
                                                   float* __restrict__ dinv,
                                                   int* __restrict__ pad_csr,
                                                   int* __restrict__ ovf_cnt,
                                                   int2* __restrict__ ovf) {
  __shared__ int pad[BUCKET_NODES * CAP];  // 32 KB
  __shared__ int lcnt[BUCKET_NODES];
  const int b = blockIdx.x;
  const int tid = threadIdx.x;
  const int node0 = b << BUCKET_SHIFT;

  if (tid < BUCKET_NODES) lcnt[tid] = 0;
  __syncthreads();

  const int n = min(bcnt[b * BCNT_STRIDE], BCAP);
  for (int k = tid; k < n; k += 256) {
    unsigned u = buf[(size_t)b * BCAP + k];
    int s = (int)(u & 0x1FFFFu);
    int dl = (int)(u >> 17);
    int slot = atomicAdd(&lcnt[dl], 1);
    if (slot < CAP) {
      pad[dl * CAP + slot] = s;
    } else {
      int p = atomicAdd(ovf_cnt, 1);
      if (p < OVF_MAX) ovf[p] = make_int2(s, node0 + dl);
    }
  }
  // fold in pass-A overflow entries belonging to this bucket (expected 0)
  int na = min(*ovfA_cnt, OVF_MAX);
  for (int t = tid; t < na; t += 256) {
    int2 p = ovfA[t];
    if ((p.y >> BUCKET_SHIFT) == b) {
      int dl = p.y & (BUCKET_NODES - 1);
      int slot = atomicAdd(&lcnt[dl], 1);
      if (slot < CAP) {
        pad[dl * CAP + slot] = p.x;
      } else {
        int q = atomicAdd(ovf_cnt, 1);
        if (q < OVF_MAX) ovf[q] = make_int2(p.x, p.y);
      }
    }
  }
  __syncthreads();

  constexpr int I4PN = CAP / 4;  // int4 per node row (16)
  for (int q = tid; q < BUCKET_NODES * I4PN; q += 256) {
    int dl = q / I4PN;
    int gn = node0 + dl;
    if (gn < NNODES) {
      int c = (q % I4PN) * 4;
      *(int4*)&pad_csr[(size_t)gn * CAP + c] = *(const int4*)&pad[dl * CAP + c];
    }
  }
  if (tid < BUCKET_NODES && node0 + tid < NNODES) {
    int c = lcnt[tid];
    cnt[node0 + tid] = c;
    dinv[node0 + tid] = rsqrtf((float)(c + 1));
  }
}

// ---------------------------------------------------------------------------
// Gather over UNSCALED fp16 rows h[i] with per-edge normalization:
//   agg[i] = di*h[i]_selfterm... specifically
//   sum_i = di*h[i] + SUM_j dinv[s_j]*h[s_j];  out = act(di*sum + bias)
// ---------------------------------------------------------------------------
struct F8 {
  float x0, x1, x2, x3, x4, x5, x6, x7;
};

__device__ __forceinline__ void add_h8s(F8& a, const __half* p, float s) {
  int4 r = *(const int4*)p;  // 8 halves
  const __half2* h = (const __half2*)&r;
  float2 f0 = __half22float2(h[0]);
  float2 f1 = __half22float2(h[1]);
  float2 f2 = __half22float2(h[2]);
  float2 f3 = __half22float2(h[3]);
  a.x0 = fmaf(s, f0.x, a.x0); a.x1 = fmaf(s, f0.y, a.x1);
  a.x2 = fmaf(s, f1.x, a.x2); a.x3 = fmaf(s, f1.y, a.x3);
  a.x4 = fmaf(s, f2.x, a.x4); a.x5 = fmaf(s, f2.y, a.x5);
  a.x6 = fmaf(s, f3.x, a.x6); a.x7 = fmaf(s, f3.y, a.x7);
}

// ===========================================================================
// fusedG: 512 threads / 64 nodes per block.
//   phase 1 (gather): hidden = relu(di*(di*h1[i] + SUM dinv[s]*h1[s]) + b1)
//                     -> LDS tile [64][128] fp16 (never written to HBM)
//   phase 2 (GEMM2):  h2 = fp16(hidden_tile @ W2), 8 waves, MFMA 16x16x32
// ===========================================================================
__global__ __launch_bounds__(512) void gather1_gemm2_kernel(
    const int* __restrict__ cnt, const int* __restrict__ pad_csr,
    const float* __restrict__ dinv, const __half* __restrict__ h1,
    const float* __restrict__ b1, const float* __restrict__ W2,
    const int* __restrict__ ovf_cnt, const int2* __restrict__ ovf,
    _Float16* __restrict__ h2) {
  constexpr int K = HID_C, N = OUT_C, KP = K + 8;  // 136
  __shared__ alignas(16) _Float16 Hl[64 * KP];   // 17408 B hidden tile [m][k]
  __shared__ alignas(16) _Float16 W2l[N * KP];   // 17408 B W2 [n][k]
  const int tid = threadIdx.x;
  const int node0 = blockIdx.x * 64;

  // ---- stage W2 (K x N fp32 row-major) -> W2l[n][k] fp16 ----
  constexpr int TILES = (K / 4) * (N / 4);  // 512
  for (int tile = tid; tile < TILES; tile += 512) {
    int kt = tile / (N / 4);
    int nt = tile % (N / 4);
    const float* wp = &W2[(4 * kt) * N + 4 * nt];
    float4 r0 = *(const float4*)(wp);
    float4 r1 = *(const float4*)(wp + N);
    float4 r2 = *(const float4*)(wp + 2 * N);
    float4 r3 = *(const float4*)(wp + 3 * N);
    half4 c0 = {(_Float16)r0.x, (_Float16)r1.x, (_Float16)r2.x, (_Float16)r3.x};
    half4 c1 = {(_Float16)r0.y, (_Float16)r1.y, (_Float16)r2.y, (_Float16)r3.y};
    half4 c2 = {(_Float16)r0.z, (_Float16)r1.z, (_Float16)r2.z, (_Float16)r3.z};
    half4 c3 = {(_Float16)r0.w, (_Float16)r1.w, (_Float16)r2.w, (_Float16)r3.w};
    *(half4*)&W2l[(4 * nt + 0) * KP + 4 * kt] = c0;
    *(half4*)&W2l[(4 * nt + 1) * KP + 4 * kt] = c1;
    *(half4*)&W2l[(4 * nt + 2) * KP + 4 * kt] = c2;
    *(half4*)&W2l[(4 * nt + 3) * KP + 4 * kt] = c3;
  }

  // ---- gather phase: 8 lanes per node, 16 channels per lane ----
  const int il = tid >> 3;            // local node 0..63
  const int c16 = (tid & 7) * 16;     // channel base
  const int i = node0 + il;

  float o[16];
#pragma unroll
  for (int q = 0; q < 16; ++q) o[q] = 0.f;

  if (i < NNODES) {
    const float di = dinv[i];
    const int deg = cnt[i];
    const int beg = i * CAP;
    const int end = beg + min(deg, CAP);
    const int* __restrict__ lst = pad_csr;
    const __half* __restrict__ Hb = h1 + c16;

    F8 a0l = {}, a0h = {}, a1l = {}, a1h = {};
    {
      const __half* p = Hb + (size_t)i * K;  // self term, weight di
      add_h8s(a0l, p, di);
      add_h8s(a0h, p + 8, di);
    }
    int j = beg;
    for (; j + 8 <= end; j += 8) {
      int4 sa = *(const int4*)&lst[j];
      int4 sb = *(const int4*)&lst[j + 4];
      float d0 = dinv[sa.x], d1 = dinv[sa.y], d2 = dinv[sa.z], d3 = dinv[sa.w];
      float d4 = dinv[sb.x], d5 = dinv[sb.y], d6 = dinv[sb.z], d7 = dinv[sb.w];
      const __half* p0 = Hb + (size_t)sa.x * K;
      const __half* p1 = Hb + (size_t)sa.y * K;
      const __half* p2 = Hb + (size_t)sa.z * K;
      const __half* p3 = Hb + (size_t)sa.w * K;
      add_h8s(a0l, p0, d0); add_h8s(a0h, p0 + 8, d0);
      add_h8s(a1l, p1, d1); add_h8s(a1h, p1 + 8, d1);
      add_h8s(a0l, p2, d2); add_h8s(a0h, p2 + 8, d2);
      add_h8s(a1l, p3, d3); add_h8s(a1h, p3 + 8, d3);
      const __half* p4 = Hb + (size_t)sb.x * K;
      const __half* p5 = Hb + (size_t)sb.y * K;
      const __half* p6 = Hb + (size_t)sb.z * K;
      const __half* p7 = Hb + (size_t)sb.w * K;
      add_h8s(a0l, p4, d4); add_h8s(a0h, p4 + 8, d4);
      add_h8s(a1l, p5, d5); add_h8s(a1h, p5 + 8, d5);
      add_h8s(a0l, p6, d6); add_h8s(a0h, p6 + 8, d6);
      add_h8s(a1l, p7, d7); add_h8s(a1h, p7 + 8, d7);
    }
    for (; j < end; ++j) {
      int s = lst[j];
      float ds = dinv[s];
      const __half* p0 = Hb + (size_t)s * K;
      add_h8s(a0l, p0, ds); add_h8s(a0h, p0 + 8, ds);
    }
    if (deg > CAP) {  // exactness guard; never taken for Poisson(16)
      int nv = min(*ovf_cnt, OVF_MAX);
      for (int t = 0; t < nv; ++t) {
        int2 p = ovf[t];
        if (p.y == i) {
          float ds = dinv[p.x];
          const __half* q = Hb + (size_t)p.x * K;
          add_h8s(a0l, q, ds); add_h8s(a0h, q + 8, ds);
        }
      }
    }
    float4 bb0 = *(const float4*)&b1[c16];
    float4 bb1 = *(const float4*)&b1[c16 + 4];
    float4 bb2 = *(const float4*)&b1[c16 + 8];
    float4 bb3 = *(const float4*)&b1[c16 + 12];
    o[0] = fmaf(a0l.x0 + a1l.x0, di, bb0.x);
    o[1] = fmaf(a0l.x1 + a1l.x1, di, bb0.y);
    o[2] = fmaf(a0l.x2 + a1l.x2, di, bb0.z);
    o[3] = fmaf(a0l.x3 + a1l.x3, di, bb0.w);
    o[4] = fmaf(a0l.x4 + a1l.x4, di, bb1.x);
    o[5] = fmaf(a0l.x5 + a1l.x5, di, bb1.y);
    o[6] = fmaf(a0l.x6 + a1l.x6, di, bb1.z);
    o[7] = fmaf(a0l.x7 + a1l.x7, di, bb1.w);
    o[8] = fmaf(a0h.x0 + a1h.x0, di, bb2.x);
    o[9] = fmaf(a0h.x1 + a1h.x1, di, bb2.y);
    o[10] = fmaf(a0h.x2 + a1h.x2, di, bb2.z);
    o[11] = fmaf(a0h.x3 + a1h.x3, di, bb2.w);
    o[12] = fmaf(a0h.x4 + a1h.x4, di, bb3.x);
    o[13] = fmaf(a0h.x5 + a1h.x5, di, bb3.y);
    o[14] = fmaf(a0h.x6 + a1h.x6, di, bb3.z);
    o[15] = fmaf(a0h.x7 + a1h.x7, di, bb3.w);
#pragma unroll
    for (int q = 0; q < 16; ++q) o[q] = o[q] > 0.f ? o[q] : 0.f;  // relu
  }
  {
    half8 hv0 = {(_Float16)o[0], (_Float16)o[1], (_Float16)o[2], (_Float16)o[3],
                 (_Float16)o[4], (_Float16)o[5], (_Float16)o[6], (_Float16)o[7]};
    half8 hv1 = {(_Float16)o[8], (_Float16)o[9], (_Float16)o[10], (_Float16)o[11],
                 (_Float16)o[12], (_Float16)o[13], (_Float16)o[14], (_Float16)o[15]};
    *(half8*)&Hl[il * KP + c16] = hv0;
    *(half8*)&Hl[il * KP + c16 + 8] = hv1;
  }
  __syncthreads();

  // ---- GEMM2 phase: 8 waves; wave w does rows (w&3)*16.., cols (w>>2)*32..
  const int w = tid >> 6;
  const int lane = tid & 63;
  const int g = lane >> 4;
  const int mi = lane & 15;
  const int wrow = (w & 3) * 16;
  const int wcol = (w >> 2) * 32;

  floatx4 acc[2];
  acc[0] = (floatx4){0.f, 0.f, 0.f, 0.f};
  acc[1] = (floatx4){0.f, 0.f, 0.f, 0.f};
  const _Float16* arow = &Hl[(wrow + mi) * KP];
#pragma unroll
  for (int ks = 0; ks < K / 32; ++ks) {
    half8 a = *(const half8*)(arow + ks * 32 + g * 8);
#pragma unroll
    for (int t = 0; t < 2; ++t) {
      half8 b = *(const half8*)&W2l[(wcol + t * 16 + mi) * KP + ks * 32 + g * 8];
      acc[t] = __builtin_amdgcn_mfma_f32_16x16x32_f16(a, b, acc[t], 0, 0, 0);
    }
  }
#pragma unroll
  for (int r = 0; r < 4; ++r) {
    int grow = node0 + wrow + 4 * g + r;
    if (grow < NNODES) {
      _Float16* orow = h2 + (size_t)grow * N + wcol + mi;
#pragma unroll
      for (int t = 0; t < 2; ++t) orow[t * 16] = (_Float16)acc[t][r];
    }
  }
}

// ===========================================================================
// gather2: out[i] = di*(di*h2[i] + SUM dinv[s]*h2[s]) + b2   (fp32, no relu)
// TPN=4 lanes/node over C=64.
// ===========================================================================
__global__ __launch_bounds__(256) void gather2_kernel(
    const int* __restrict__ cnt, const int* __restrict__ pad_csr,
    const float* __restrict__ dinv, const __half* __restrict__ h2,
    const float* __restrict__ b2, const int* __restrict__ ovf_cnt,
    const int2* __restrict__ ovf, float* __restrict__ Out) {
  constexpr int C = OUT_C;
  constexpr int TPN = C / 16;  // 4
  int gid = blockIdx.x * 256 + threadIdx.x;
  int i = gid / TPN;
  int c16 = (gid % TPN) * 16;
  if (i >= NNODES) return;

  const float di = dinv[i];
  const int deg = cnt[i];
  const int beg = i * CAP;
  const int end = beg + min(deg, CAP);
  const int* __restrict__ lst = pad_csr;
  const __half* __restrict__ Hb = h2 + c16;

  F8 a0l = {}, a0h = {}, a1l = {}, a1h = {};
  {
    const __half* p = Hb + (size_t)i * C;
    add_h8s(a0l, p, di);
    add_h8s(a0h, p + 8, di);
  }
  int j = beg;
  for (; j + 8 <= end; j += 8) {
    int4 sa = *(const int4*)&lst[j];
    int4 sb = *(const int4*)&lst[j + 4];
    float d0 = dinv[sa.x], d1 = dinv[sa.y], d2 = dinv[sa.z], d3 = dinv[sa.w];
    float d4 = dinv[sb.x], d5 = dinv[sb.y], d6 = dinv[sb.z], d7 = dinv[sb.w];
    const __half* p0 = Hb + (size_t)sa.x * C;
    const __half* p1 = Hb + (size_t)sa.y * C;
    const __half* p2 = Hb + (size_t)sa.z * C;
    const __half* p3 = Hb + (size_t)sa.w * C;
    add_h8s(a0l, p0, d0); add_h8s(a0h, p0 + 8, d0);
    add_h8s(a1l, p1, d1); add_h8s(a1h, p1 + 8, d1);
    add_h8s(a0l, p2, d2); add_h8s(a0h, p2 + 8, d2);
    add_h8s(a1l, p3, d3); add_h8s(a1h, p3 + 8, d3);
    const __half* p4 = Hb + (size_t)sb.x * C;
    const __half* p5 = Hb + (size_t)sb.y * C;
    const __half* p6 = Hb + (size_t)sb.z * C;
    const __half* p7 = Hb + (size_t)sb.w * C;
    add_h8s(a0l, p4, d4); add_h8s(a0h, p4 + 8, d4);
    add_h8s(a1l, p5, d5); add_h8s(a1h, p5 + 8, d5);
    add_h8s(a0l, p6, d6); add_h8s(a0h, p6 + 8, d6);
    add_h8s(a1l, p7, d7); add_h8s(a1h, p7 + 8, d7);
  }
  for (; j < end; ++j) {
    int s = lst[j];
    float ds = dinv[s];
    const __half* p0 = Hb + (size_t)s * C;
    add_h8s(a0l, p0, ds); add_h8s(a0h, p0 + 8, ds);
  }
  if (deg > CAP) {
    int nv = min(*ovf_cnt, OVF_MAX);
    for (int t = 0; t < nv; ++t) {
      int2 p = ovf[t];
      if (p.y == i) {
        float ds = dinv[p.x];
        const __half* q = Hb + (size_t)p.x * C;
        add_h8s(a0l, q, ds); add_h8s(a0h, q + 8, ds);
      }
    }
  }

  float4 bb0 = *(const float4*)&b2[c16];
  float4 bb1 = *(const float4*)&b2[c16 + 4];
  float4 bb2 = *(const float4*)&b2[c16 + 8];
  float4 bb3 = *(const float4*)&b2[c16 + 12];
  float* O = Out + (size_t)i * C + c16;
  *(float4*)O = make_float4(fmaf(a0l.x0 + a1l.x0, di, bb0.x),
                            fmaf(a0l.x1 + a1l.x1, di, bb0.y),
                            fmaf(a0l.x2 + a1l.x2, di, bb0.z),
                            fmaf(a0l.x3 + a1l.x3, di, bb0.w));
  *(float4*)(O + 4) = make_float4(fmaf(a0l.x4 + a1l.x4, di, bb1.x),
                                  fmaf(a0l.x5 + a1l.x5, di, bb1.y),
                                  fmaf(a0l.x6 + a1l.x6, di, bb1.z),
                                  fmaf(a0l.x7 + a1l.x7, di, bb1.w));
  *(float4*)(O + 8) = make_float4(fmaf(a0h.x0 + a1h.x0, di, bb2.x),
                                  fmaf(a0h.x1 + a1h.x1, di, bb2.y),
                                  fmaf(a0h.x2 + a1h.x2, di, bb2.z),
                                  fmaf(a0h.x3 + a1h.x3, di, bb2.w));
  *(float4*)(O + 12) = make_float4(fmaf(a0h.x4 + a1h.x4, di, bb3.x),
                                   fmaf(a0h.x5 + a1h.x5, di, bb3.y),
                                   fmaf(a0h.x6 + a1h.x6, di, bb3.z),
                                   fmaf(a0h.x7 + a1h.x7, di, bb3.w));
}

// ===========================================================================
// Launch (5 kernels)
// ===========================================================================
extern "C" void kernel_launch(void* const* d_in, const int* in_sizes, int n_in,
                              void* d_out, int out_size, void* d_ws, size_t ws_size,
                              hipStream_t stream) {
  const float* x = (const float*)d_in[0];
  const void* eidx = d_in[1];
  const float* W1 = (const float*)d_in[2];
  const float* b1 = (const float*)d_in[3];
  const float* W2 = (const float*)d_in[4];
  const float* b2 = (const float*)d_in[5];
  float* out = (float*)d_out;
  char* ws = (char*)d_ws;

  // Workspace layout (512B-aligned, ~74.5 MB; harness provides >=110 MB):
  int*      flag     = (int*)(ws + 0);             //         4 B
  int*      ovf_cnt  = (int*)(ws + 512);           //         4 B
  int*      ovfA_cnt = (int*)(ws + 1024);          //         4 B
  int*      bcnt     = (int*)(ws + 1536);          //    50,048 B (782*16, padded)
  int*      cnt      = (int*)(ws + 52224);         //   400,000 B
  float*    dinv     = (float*)(ws + 452608);      //   400,000 B
  int2*     ovf      = (int2*)(ws + 852992);       //    32,768 B
  int2*     ovfA     = (int2*)(ws + 885760);       //    32,768 B
  unsigned* buf      = (unsigned*)(ws + 918528);   // 9,609,216 B (782*3072*4)
  int*      pad_csr  = (int*)(ws + 10528256);      // 25,600,000 B (100k x 64)
  _Float16* h1       = (_Float16*)(ws + 36128256); // 25,600,000 B (fp16, unscaled)
  _Float16* h2       = (_Float16*)(ws + 61728256); // 12,800,000 B (fp16, unscaled)

  zero_detect_kernel<<<(NB * BCNT_STRIDE + 255) / 256, 256, 0, stream>>>(
      eidx, flag, bcnt, ovf_cnt, ovfA_cnt);
  binA_gemm1_kernel<<<NBLK_A + GB, 256, 0, stream>>>(eidx, flag, bcnt, buf,
                                                     ovfA_cnt, ovfA, x, W1, h1);
  binB_kernel<<<NB, 256, 0, stream>>>(bcnt, buf, ovfA_cnt, ovfA, cnt, dinv,
                                      pad_csr, ovf_cnt, ovf);
  gather1_gemm2_kernel<<<GB, 512, 0, stream>>>(cnt, pad_csr, dinv,
                                               (const __half*)h1, b1, W2,
                                               ovf_cnt, ovf, h2);
  gather2_kernel<<<(NNODES * (OUT_C / 16) + 255) / 256, 256, 0, stream>>>(
      cnt, pad_csr, dinv, (const __half*)h2, b2, ovf_cnt, ovf, out);
}